// Round 1
// baseline (1033.301 us; speedup 1.0000x reference)
//
#include <hip/hip_runtime.h>

#define N_NODES 100000
#define N_EDGES 1600000
#define F_IN    128
#define HC      128     // H * C
#define NGRAPH  64
#define NEG_SLOPE 0.2f

static constexpr int SCAN_NB = (N_NODES + 255) / 256;   // 391
static constexpr int TOT_E   = N_EDGES + N_NODES;       // with self loops

// ---------------- CSR build ----------------

__global__ __launch_bounds__(256) void hist_kernel(const int* __restrict__ ei, int* __restrict__ deg) {
    int i = blockIdx.x * 256 + threadIdx.x;
    if (i < N_EDGES) {
        atomicAdd(&deg[ei[N_EDGES + i]], 1);      // dst of real edge
    } else if (i < TOT_E) {
        atomicAdd(&deg[i - N_EDGES], 1);          // self loop
    }
}

__global__ __launch_bounds__(256) void scan_partial(const int* __restrict__ deg, int* __restrict__ bsum) {
    int i = blockIdx.x * 256 + threadIdx.x;
    int d = (i < N_NODES) ? deg[i] : 0;
    for (int off = 32; off; off >>= 1) d += __shfl_down(d, off);
    __shared__ int wsum[4];
    int lane = threadIdx.x & 63, w = threadIdx.x >> 6;
    if (lane == 0) wsum[w] = d;
    __syncthreads();
    if (threadIdx.x == 0) bsum[blockIdx.x] = wsum[0] + wsum[1] + wsum[2] + wsum[3];
}

__global__ void scan_bsum(const int* __restrict__ bsum, int* __restrict__ boff) {
    __shared__ int sd[512];
    int t = threadIdx.x;
    int v = (t < SCAN_NB) ? bsum[t] : 0;
    sd[t] = v; __syncthreads();
    for (int off = 1; off < 512; off <<= 1) {
        int x = (t >= off) ? sd[t - off] : 0;
        __syncthreads();
        sd[t] += x;
        __syncthreads();
    }
    if (t < SCAN_NB) boff[t] = sd[t] - v;   // exclusive
}

__global__ __launch_bounds__(256) void scan_final(const int* __restrict__ deg, const int* __restrict__ boff,
                                                  int* __restrict__ offs, int* __restrict__ cursor) {
    __shared__ int sd[256];
    int t = threadIdx.x;
    int i = blockIdx.x * 256 + t;
    int d = (i < N_NODES) ? deg[i] : 0;
    sd[t] = d; __syncthreads();
    for (int off = 1; off < 256; off <<= 1) {
        int x = (t >= off) ? sd[t - off] : 0;
        __syncthreads();
        sd[t] += x;
        __syncthreads();
    }
    int incl = sd[t];
    int base = boff[blockIdx.x];
    if (i < N_NODES) {
        offs[i + 1] = base + incl;
        cursor[i]   = base + incl - d;
    }
    if (i == 0) offs[0] = 0;
}

__global__ __launch_bounds__(256) void scatter_kernel(const int* __restrict__ ei, int* __restrict__ cursor,
                                                      int* __restrict__ csr_src) {
    int i = blockIdx.x * 256 + threadIdx.x;
    int s, d;
    if (i < N_EDGES)      { s = ei[i]; d = ei[N_EDGES + i]; }
    else if (i < TOT_E)   { s = i - N_EDGES; d = s; }
    else return;
    int pos = atomicAdd(&cursor[d], 1);
    csr_src[pos] = s;
}

__global__ __launch_bounds__(256) void counts_kernel(const int* __restrict__ batch, int* __restrict__ counts) {
    __shared__ int loc[NGRAPH];
    int t = threadIdx.x;
    if (t < NGRAPH) loc[t] = 0;
    __syncthreads();
    int i = blockIdx.x * 256 + t;
    if (i < N_NODES) atomicAdd(&loc[batch[i]], 1);
    __syncthreads();
    if (t < NGRAPH && loc[t]) atomicAdd(&counts[t], loc[t]);
}

// ---------------- GEMM: H = X @ W  (K = 128, COUT = 128) ----------------
// block = 256 threads, tile = 64 rows x 128 cols; thread computes 8 rows x 4 cols.

__global__ __launch_bounds__(256) void gemm_kernel(const float* __restrict__ X, const float* __restrict__ W,
                                                   float* __restrict__ Hout) {
    __shared__ float xs[64][F_IN];     // 32 KB
    int t = threadIdx.x;
    int base = blockIdx.x * 64;
    // load 64x128 x-tile (float4, coalesced)
    for (int i = t; i < 64 * F_IN / 4; i += 256) {
        int row = i >> 5;          // 32 float4 per row
        int c4  = i & 31;
        float4 v = make_float4(0.f, 0.f, 0.f, 0.f);
        if (base + row < N_NODES) v = ((const float4*)X)[(size_t)(base + row) * 32 + c4];
        *(float4*)&xs[row][c4 * 4] = v;
    }
    __syncthreads();

    int tc = t & 31;     // channel group -> channels tc*4 .. tc*4+3
    int tn = t >> 5;     // row group    -> rows tn*8 .. tn*8+7
    float acc[8][4] = {};
    const float4* Wv = (const float4*)W;
#pragma unroll 4
    for (int k = 0; k < F_IN; k += 4) {
        float4 w0 = Wv[(k + 0) * 32 + tc];
        float4 w1 = Wv[(k + 1) * 32 + tc];
        float4 w2 = Wv[(k + 2) * 32 + tc];
        float4 w3 = Wv[(k + 3) * 32 + tc];
#pragma unroll
        for (int j = 0; j < 8; ++j) {
            float4 xv = *(const float4*)&xs[tn * 8 + j][k];
            acc[j][0] = fmaf(xv.w, w3.x, fmaf(xv.z, w2.x, fmaf(xv.y, w1.x, fmaf(xv.x, w0.x, acc[j][0]))));
            acc[j][1] = fmaf(xv.w, w3.y, fmaf(xv.z, w2.y, fmaf(xv.y, w1.y, fmaf(xv.x, w0.y, acc[j][1]))));
            acc[j][2] = fmaf(xv.w, w3.z, fmaf(xv.z, w2.z, fmaf(xv.y, w1.z, fmaf(xv.x, w0.z, acc[j][2]))));
            acc[j][3] = fmaf(xv.w, w3.w, fmaf(xv.z, w2.w, fmaf(xv.y, w1.w, fmaf(xv.x, w0.w, acc[j][3]))));
        }
    }
#pragma unroll
    for (int j = 0; j < 8; ++j) {
        int row = base + tn * 8 + j;
        if (row < N_NODES)
            *(float4*)&Hout[(size_t)row * HC + tc * 4] = make_float4(acc[j][0], acc[j][1], acc[j][2], acc[j][3]);
    }
}

// ---------------- per-node attention logits ----------------
// one wave per node; lane l holds channels 2l, 2l+1 (head = l>>5)

__global__ __launch_bounds__(256) void alpha_kernel(const float* __restrict__ H,
                                                    const float* __restrict__ a_src, const float* __restrict__ a_dst,
                                                    float* __restrict__ asrc, float* __restrict__ adst) {
    int wid  = (blockIdx.x * 256 + threadIdx.x) >> 6;
    int lane = threadIdx.x & 63;
    if (wid >= N_NODES) return;
    float2 hv = *(const float2*)&H[(size_t)wid * HC + lane * 2];
    int ch = lane * 2;
    float2 as = *(const float2*)&a_src[ch];   // a_src is [2][64] flat = 128 floats
    float2 ad = *(const float2*)&a_dst[ch];
    float ps = hv.x * as.x + hv.y * as.y;
    float pd = hv.x * ad.x + hv.y * ad.y;
    for (int off = 16; off; off >>= 1) {      // reduce within each 32-lane half (one head each)
        ps += __shfl_xor(ps, off);
        pd += __shfl_xor(pd, off);
    }
    int head = lane >> 5;
    if ((lane & 31) == 0) {
        asrc[wid * 2 + head] = ps;
        adst[wid * 2 + head] = pd;
    }
}

// ---------------- aggregation: one wave per dst node ----------------

__global__ __launch_bounds__(256) void agg_kernel(const int* __restrict__ offs, const int* __restrict__ csr_src,
                                                  const float* __restrict__ asrc, const float* __restrict__ adst,
                                                  const float* __restrict__ Hin, const float* __restrict__ bias,
                                                  float* __restrict__ Hout, int do_relu) {
    int wid  = (blockIdx.x * 256 + threadIdx.x) >> 6;
    int lane = threadIdx.x & 63;
    if (wid >= N_NODES) return;
    int beg = offs[wid], end = offs[wid + 1];
    int head = lane >> 5;
    float madst = adst[wid * 2 + head];

    float den = 0.f;
    for (int e = beg; e < end; ++e) {
        int s = csr_src[e];
        float el = asrc[s * 2 + head] + madst;
        el = el > 0.f ? el : NEG_SLOPE * el;
        den += __expf(el);
    }
    float inv = 1.0f / den;

    float2 acc = make_float2(0.f, 0.f);
    for (int e = beg; e < end; ++e) {
        int s = csr_src[e];
        float el = asrc[s * 2 + head] + madst;
        el = el > 0.f ? el : NEG_SLOPE * el;
        float w = __expf(el) * inv;
        float2 hv = *(const float2*)&Hin[(size_t)s * HC + lane * 2];
        acc.x = fmaf(w, hv.x, acc.x);
        acc.y = fmaf(w, hv.y, acc.y);
    }
    int ch = lane * 2;
    float o0 = acc.x + bias[ch];
    float o1 = acc.y + bias[ch + 1];
    if (do_relu) {
        o0 = fmaxf(o0, 0.f);
        o1 = fmaxf(o1, 0.f);
    }
    *(float2*)&Hout[(size_t)wid * HC + ch] = make_float2(o0, o1);
}

// ---------------- mean pool (batch is sorted -> contiguous ranges) ----------------
// grid (G, 8): block sums a chunk of graph g's rows; scaled atomicAdd into out.

__global__ __launch_bounds__(256) void pool_kernel(const float* __restrict__ H2, const int* __restrict__ counts,
                                                   float* __restrict__ out) {
    int g = blockIdx.x;
    int chunk = blockIdx.y;
    __shared__ int soff, scnt;
    if (threadIdx.x == 0) {
        int s = 0;
        for (int i = 0; i < g; ++i) s += counts[i];
        soff = s; scnt = counts[g];
    }
    __syncthreads();
    int start = soff, cnt = scnt;
    int r = threadIdx.x >> 7;       // 0..1
    int c = threadIdx.x & 127;
    float acc = 0.f;
    for (int v = chunk * 2 + r; v < cnt; v += 16)
        acc += H2[(size_t)(start + v) * HC + c];
    float inv = 1.0f / fmaxf((float)cnt, 1.0f);
    atomicAdd(&out[g * HC + c], acc * inv);
}

// ---------------- launch ----------------

extern "C" void kernel_launch(void* const* d_in, const int* in_sizes, int n_in,
                              void* d_out, int out_size, void* d_ws, size_t ws_size,
                              hipStream_t stream) {
    const float* x     = (const float*)d_in[0];
    const int*   ei    = (const int*)d_in[1];
    const int*   batch = (const int*)d_in[2];
    const float* W1    = (const float*)d_in[3];
    const float* a1s   = (const float*)d_in[4];
    const float* a1d   = (const float*)d_in[5];
    const float* b1    = (const float*)d_in[6];
    const float* W2    = (const float*)d_in[7];
    const float* a2s   = (const float*)d_in[8];
    const float* a2d   = (const float*)d_in[9];
    const float* b2    = (const float*)d_in[10];
    float* out = (float*)d_out;

    char* ws = (char*)d_ws;
    const size_t SZ_H = (size_t)N_NODES * HC * sizeof(float);   // 51.2 MB
    float* hA   = (float*)(ws);
    float* hB   = (float*)(ws + SZ_H);
    float* asrc = (float*)(ws + 2 * SZ_H);
    float* adst = asrc + (size_t)N_NODES * 2;
    int*   deg  = (int*)(adst + (size_t)N_NODES * 2);
    int*   offs = deg + (N_NODES + 1);
    int*   cursor = offs + (N_NODES + 1);
    int*   csr  = cursor + N_NODES;
    int*   bsum = csr + TOT_E;
    int*   boff = bsum + SCAN_NB;
    int*   counts = boff + SCAN_NB;

    // zero accumulators
    hipMemsetAsync(deg, 0, (N_NODES + 1) * sizeof(int), stream);
    hipMemsetAsync(counts, 0, NGRAPH * sizeof(int), stream);
    hipMemsetAsync(out, 0, (size_t)out_size * sizeof(float), stream);

    int histBlocks = (TOT_E + 255) / 256;
    hist_kernel<<<histBlocks, 256, 0, stream>>>(ei, deg);
    counts_kernel<<<(N_NODES + 255) / 256, 256, 0, stream>>>(batch, counts);
    scan_partial<<<SCAN_NB, 256, 0, stream>>>(deg, bsum);
    scan_bsum<<<1, 512, 0, stream>>>(bsum, boff);
    scan_final<<<SCAN_NB, 256, 0, stream>>>(deg, boff, offs, cursor);
    scatter_kernel<<<histBlocks, 256, 0, stream>>>(ei, cursor, csr);

    int gemmBlocks = (N_NODES + 63) / 64;
    int waveBlocks = (N_NODES + 3) / 4;       // 4 waves per 256-thread block

    // layer 1
    gemm_kernel<<<gemmBlocks, 256, 0, stream>>>(x, W1, hA);
    alpha_kernel<<<waveBlocks, 256, 0, stream>>>(hA, a1s, a1d, asrc, adst);
    agg_kernel<<<waveBlocks, 256, 0, stream>>>(offs, csr, asrc, adst, hA, b1, hB, 1);

    // layer 2
    gemm_kernel<<<gemmBlocks, 256, 0, stream>>>(hB, W2, hA);
    alpha_kernel<<<waveBlocks, 256, 0, stream>>>(hA, a2s, a2d, asrc, adst);
    agg_kernel<<<waveBlocks, 256, 0, stream>>>(offs, csr, asrc, adst, hA, b2, hB, 0);

    // pool
    pool_kernel<<<dim3(NGRAPH, 8), 256, 0, stream>>>(hB, counts, out);
}

// Round 2
// 683.610 us; speedup vs baseline: 1.5115x; 1.5115x over previous
//
#include <hip/hip_runtime.h>

#define N_NODES 100000
#define N_EDGES 1600000
#define F_IN    128
#define HC      128     // H * C
#define NGRAPH  64
#define NEG_SLOPE 0.2f

static constexpr int SCAN_NB = (N_NODES + 255) / 256;   // 391
static constexpr int TOT_E   = N_EDGES + N_NODES;       // with self loops

// ---------------- CSR build ----------------

__global__ __launch_bounds__(256) void hist_kernel(const int* __restrict__ ei, int* __restrict__ deg) {
    int i = blockIdx.x * 256 + threadIdx.x;
    if (i < N_EDGES) {
        atomicAdd(&deg[ei[N_EDGES + i]], 1);      // dst of real edge
    } else if (i < TOT_E) {
        atomicAdd(&deg[i - N_EDGES], 1);          // self loop
    }
}

__global__ __launch_bounds__(256) void scan_partial(const int* __restrict__ deg, int* __restrict__ bsum) {
    int i = blockIdx.x * 256 + threadIdx.x;
    int d = (i < N_NODES) ? deg[i] : 0;
    for (int off = 32; off; off >>= 1) d += __shfl_down(d, off);
    __shared__ int wsum[4];
    int lane = threadIdx.x & 63, w = threadIdx.x >> 6;
    if (lane == 0) wsum[w] = d;
    __syncthreads();
    if (threadIdx.x == 0) bsum[blockIdx.x] = wsum[0] + wsum[1] + wsum[2] + wsum[3];
}

__global__ void scan_bsum(const int* __restrict__ bsum, int* __restrict__ boff) {
    __shared__ int sd[512];
    int t = threadIdx.x;
    int v = (t < SCAN_NB) ? bsum[t] : 0;
    sd[t] = v; __syncthreads();
    for (int off = 1; off < 512; off <<= 1) {
        int x = (t >= off) ? sd[t - off] : 0;
        __syncthreads();
        sd[t] += x;
        __syncthreads();
    }
    if (t < SCAN_NB) boff[t] = sd[t] - v;   // exclusive
}

__global__ __launch_bounds__(256) void scan_final(const int* __restrict__ deg, const int* __restrict__ boff,
                                                  int* __restrict__ offs, int* __restrict__ cursor) {
    __shared__ int sd[256];
    int t = threadIdx.x;
    int i = blockIdx.x * 256 + t;
    int d = (i < N_NODES) ? deg[i] : 0;
    sd[t] = d; __syncthreads();
    for (int off = 1; off < 256; off <<= 1) {
        int x = (t >= off) ? sd[t - off] : 0;
        __syncthreads();
        sd[t] += x;
        __syncthreads();
    }
    int incl = sd[t];
    int base = boff[blockIdx.x];
    if (i < N_NODES) {
        offs[i + 1] = base + incl;
        cursor[i]   = base + incl - d;
    }
    if (i == 0) offs[0] = 0;
}

__global__ __launch_bounds__(256) void scatter_kernel(const int* __restrict__ ei, int* __restrict__ cursor,
                                                      int* __restrict__ csr_src, int* __restrict__ epos) {
    int i = blockIdx.x * 256 + threadIdx.x;
    int s, d;
    if (i < N_EDGES)      { s = ei[i]; d = ei[N_EDGES + i]; }
    else if (i < TOT_E)   { s = i - N_EDGES; d = s; }
    else return;
    int pos = atomicAdd(&cursor[d], 1);
    csr_src[pos] = s;
    epos[i] = pos;
}

__global__ __launch_bounds__(256) void counts_kernel(const int* __restrict__ batch, int* __restrict__ counts) {
    __shared__ int loc[NGRAPH];
    int t = threadIdx.x;
    if (t < NGRAPH) loc[t] = 0;
    __syncthreads();
    int i = blockIdx.x * 256 + t;
    if (i < N_NODES) atomicAdd(&loc[batch[i]], 1);
    __syncthreads();
    if (t < NGRAPH && loc[t]) atomicAdd(&counts[t], loc[t]);
}

// ---------------- GEMM: H = X @ W  (K = 128, COUT = 128) ----------------

__global__ __launch_bounds__(256) void gemm_kernel(const float* __restrict__ X, const float* __restrict__ W,
                                                   float* __restrict__ Hout) {
    __shared__ float xs[64][F_IN];     // 32 KB
    int t = threadIdx.x;
    int base = blockIdx.x * 64;
    for (int i = t; i < 64 * F_IN / 4; i += 256) {
        int row = i >> 5;
        int c4  = i & 31;
        float4 v = make_float4(0.f, 0.f, 0.f, 0.f);
        if (base + row < N_NODES) v = ((const float4*)X)[(size_t)(base + row) * 32 + c4];
        *(float4*)&xs[row][c4 * 4] = v;
    }
    __syncthreads();

    int tc = t & 31;
    int tn = t >> 5;
    float acc[8][4] = {};
    const float4* Wv = (const float4*)W;
#pragma unroll 4
    for (int k = 0; k < F_IN; k += 4) {
        float4 w0 = Wv[(k + 0) * 32 + tc];
        float4 w1 = Wv[(k + 1) * 32 + tc];
        float4 w2 = Wv[(k + 2) * 32 + tc];
        float4 w3 = Wv[(k + 3) * 32 + tc];
#pragma unroll
        for (int j = 0; j < 8; ++j) {
            float4 xv = *(const float4*)&xs[tn * 8 + j][k];
            acc[j][0] = fmaf(xv.w, w3.x, fmaf(xv.z, w2.x, fmaf(xv.y, w1.x, fmaf(xv.x, w0.x, acc[j][0]))));
            acc[j][1] = fmaf(xv.w, w3.y, fmaf(xv.z, w2.y, fmaf(xv.y, w1.y, fmaf(xv.x, w0.y, acc[j][1]))));
            acc[j][2] = fmaf(xv.w, w3.z, fmaf(xv.z, w2.z, fmaf(xv.y, w1.z, fmaf(xv.x, w0.z, acc[j][2]))));
            acc[j][3] = fmaf(xv.w, w3.w, fmaf(xv.z, w2.w, fmaf(xv.y, w1.w, fmaf(xv.x, w0.w, acc[j][3]))));
        }
    }
#pragma unroll
    for (int j = 0; j < 8; ++j) {
        int row = base + tn * 8 + j;
        if (row < N_NODES)
            *(float4*)&Hout[(size_t)row * HC + tc * 4] = make_float4(acc[j][0], acc[j][1], acc[j][2], acc[j][3]);
    }
}

// ---------------- per-node attention logits ----------------

__global__ __launch_bounds__(256) void alpha_kernel(const float* __restrict__ H,
                                                    const float* __restrict__ a_src, const float* __restrict__ a_dst,
                                                    float* __restrict__ asrc, float* __restrict__ adst) {
    int wid  = (blockIdx.x * 256 + threadIdx.x) >> 6;
    int lane = threadIdx.x & 63;
    if (wid >= N_NODES) return;
    float2 hv = *(const float2*)&H[(size_t)wid * HC + lane * 2];
    int ch = lane * 2;
    float2 as = *(const float2*)&a_src[ch];
    float2 ad = *(const float2*)&a_dst[ch];
    float ps = hv.x * as.x + hv.y * as.y;
    float pd = hv.x * ad.x + hv.y * ad.y;
    for (int off = 16; off; off >>= 1) {
        ps += __shfl_xor(ps, off);
        pd += __shfl_xor(pd, off);
    }
    int head = lane >> 5;
    if ((lane & 31) == 0) {
        asrc[wid * 2 + head] = ps;
        adst[wid * 2 + head] = pd;
    }
}

// ---------------- per-edge softmax numerators, written in CSR order ----------------

__global__ __launch_bounds__(256) void edgew_kernel(const int* __restrict__ ei, const int* __restrict__ epos,
                                                    const float* __restrict__ asrc, const float* __restrict__ adst,
                                                    float* __restrict__ wbuf) {
    int i = blockIdx.x * 256 + threadIdx.x;
    int s, d;
    if (i < N_EDGES)      { s = ei[i]; d = ei[N_EDGES + i]; }
    else if (i < TOT_E)   { s = i - N_EDGES; d = s; }
    else return;
    float2 as = *(const float2*)&asrc[(size_t)s * 2];
    float2 ad = *(const float2*)&adst[(size_t)d * 2];
    float e0 = as.x + ad.x; e0 = e0 > 0.f ? e0 : NEG_SLOPE * e0;
    float e1 = as.y + ad.y; e1 = e1 > 0.f ? e1 : NEG_SLOPE * e1;
    int p = epos[i];
    *(float2*)&wbuf[(size_t)p * 2] = make_float2(__expf(e0), __expf(e1));
}

// ---------------- aggregation: one wave per dst node, half-wave edge parallel ----------------
// lanes 0-31 process even CSR edges, lanes 32-63 odd edges; each lane holds float4
// (channels 4*hl .. 4*hl+3); halves combined via shfl_xor(32) at the end.

__global__ __launch_bounds__(256) void agg_kernel(const int* __restrict__ offs, const int* __restrict__ csr_src,
                                                  const float* __restrict__ wbuf,
                                                  const float* __restrict__ Hin, const float* __restrict__ bias,
                                                  float* __restrict__ Hout, int do_relu) {
    int wid  = (blockIdx.x * 256 + threadIdx.x) >> 6;
    int lane = threadIdx.x & 63;
    if (wid >= N_NODES) return;
    int beg = offs[wid], end = offs[wid + 1];
    int half = lane >> 5;
    int hl   = lane & 31;          // channels 4*hl .. 4*hl+3
    int head = hl >> 4;            // (4*hl)>>6

    float den = 0.f;
    float4 acc = make_float4(0.f, 0.f, 0.f, 0.f);

    // unrolled by 2: up to 2 independent h-row gathers in flight per half-wave (4 per wave)
    for (int e = beg + half; e < end; e += 4) {
        int e1 = e + 2;
        bool v1 = e1 < end;
        int s0 = csr_src[e];
        int s1 = v1 ? csr_src[e1] : s0;
        float w0 = wbuf[(size_t)e * 2 + head];
        float w1 = v1 ? wbuf[(size_t)e1 * 2 + head] : 0.f;
        float4 h0 = *(const float4*)&Hin[(size_t)s0 * HC + hl * 4];
        float4 h1 = *(const float4*)&Hin[(size_t)s1 * HC + hl * 4];
        den += w0 + w1;
        acc.x = fmaf(w1, h1.x, fmaf(w0, h0.x, acc.x));
        acc.y = fmaf(w1, h1.y, fmaf(w0, h0.y, acc.y));
        acc.z = fmaf(w1, h1.z, fmaf(w0, h0.z, acc.z));
        acc.w = fmaf(w1, h1.w, fmaf(w0, h0.w, acc.w));
    }

    // combine the two halves (same channel/head layout in each half)
    den   += __shfl_xor(den, 32);
    acc.x += __shfl_xor(acc.x, 32);
    acc.y += __shfl_xor(acc.y, 32);
    acc.z += __shfl_xor(acc.z, 32);
    acc.w += __shfl_xor(acc.w, 32);

    if (half == 0) {
        float inv = 1.0f / den;
        float4 b = *(const float4*)&bias[hl * 4];
        float4 o;
        o.x = fmaf(acc.x, inv, b.x);
        o.y = fmaf(acc.y, inv, b.y);
        o.z = fmaf(acc.z, inv, b.z);
        o.w = fmaf(acc.w, inv, b.w);
        if (do_relu) {
            o.x = fmaxf(o.x, 0.f); o.y = fmaxf(o.y, 0.f);
            o.z = fmaxf(o.z, 0.f); o.w = fmaxf(o.w, 0.f);
        }
        *(float4*)&Hout[(size_t)wid * HC + hl * 4] = o;
    }
}

// ---------------- mean pool ----------------

__global__ __launch_bounds__(256) void pool_kernel(const float* __restrict__ H2, const int* __restrict__ counts,
                                                   float* __restrict__ out) {
    int g = blockIdx.x;
    int chunk = blockIdx.y;
    __shared__ int soff, scnt;
    if (threadIdx.x == 0) {
        int s = 0;
        for (int i = 0; i < g; ++i) s += counts[i];
        soff = s; scnt = counts[g];
    }
    __syncthreads();
    int start = soff, cnt = scnt;
    int r = threadIdx.x >> 7;
    int c = threadIdx.x & 127;
    float acc = 0.f;
    for (int v = chunk * 2 + r; v < cnt; v += 16)
        acc += H2[(size_t)(start + v) * HC + c];
    float inv = 1.0f / fmaxf((float)cnt, 1.0f);
    atomicAdd(&out[g * HC + c], acc * inv);
}

// ---------------- launch ----------------

extern "C" void kernel_launch(void* const* d_in, const int* in_sizes, int n_in,
                              void* d_out, int out_size, void* d_ws, size_t ws_size,
                              hipStream_t stream) {
    const float* x     = (const float*)d_in[0];
    const int*   ei    = (const int*)d_in[1];
    const int*   batch = (const int*)d_in[2];
    const float* W1    = (const float*)d_in[3];
    const float* a1s   = (const float*)d_in[4];
    const float* a1d   = (const float*)d_in[5];
    const float* b1    = (const float*)d_in[6];
    const float* W2    = (const float*)d_in[7];
    const float* a2s   = (const float*)d_in[8];
    const float* a2d   = (const float*)d_in[9];
    const float* b2    = (const float*)d_in[10];
    float* out = (float*)d_out;

    char* ws = (char*)d_ws;
    const size_t SZ_H = (size_t)N_NODES * HC * sizeof(float);   // 51.2 MB
    float* hA   = (float*)(ws);
    float* hB   = (float*)(ws + SZ_H);
    float* asrc = (float*)(ws + 2 * SZ_H);
    float* adst = asrc + (size_t)N_NODES * 2;
    float* wbuf = adst + (size_t)N_NODES * 2;                   // TOT_E * 2 floats
    int*   deg  = (int*)(wbuf + (size_t)TOT_E * 2);
    int*   offs = deg + (N_NODES + 1);
    int*   cursor = offs + (N_NODES + 1);
    int*   csr  = cursor + N_NODES;
    int*   epos = csr + TOT_E;
    int*   bsum = epos + TOT_E;
    int*   boff = bsum + SCAN_NB;
    int*   counts = boff + SCAN_NB;

    hipMemsetAsync(deg, 0, (N_NODES + 1) * sizeof(int), stream);
    hipMemsetAsync(counts, 0, NGRAPH * sizeof(int), stream);
    hipMemsetAsync(out, 0, (size_t)out_size * sizeof(float), stream);

    int histBlocks = (TOT_E + 255) / 256;
    hist_kernel<<<histBlocks, 256, 0, stream>>>(ei, deg);
    counts_kernel<<<(N_NODES + 255) / 256, 256, 0, stream>>>(batch, counts);
    scan_partial<<<SCAN_NB, 256, 0, stream>>>(deg, bsum);
    scan_bsum<<<1, 512, 0, stream>>>(bsum, boff);
    scan_final<<<SCAN_NB, 256, 0, stream>>>(deg, boff, offs, cursor);
    scatter_kernel<<<histBlocks, 256, 0, stream>>>(ei, cursor, csr, epos);

    int gemmBlocks = (N_NODES + 63) / 64;
    int waveBlocks = (N_NODES + 3) / 4;

    // layer 1
    gemm_kernel<<<gemmBlocks, 256, 0, stream>>>(x, W1, hA);
    alpha_kernel<<<waveBlocks, 256, 0, stream>>>(hA, a1s, a1d, asrc, adst);
    edgew_kernel<<<histBlocks, 256, 0, stream>>>(ei, epos, asrc, adst, wbuf);
    agg_kernel<<<waveBlocks, 256, 0, stream>>>(offs, csr, wbuf, hA, b1, hB, 1);

    // layer 2
    gemm_kernel<<<gemmBlocks, 256, 0, stream>>>(hB, W2, hA);
    alpha_kernel<<<waveBlocks, 256, 0, stream>>>(hA, a2s, a2d, asrc, adst);
    edgew_kernel<<<histBlocks, 256, 0, stream>>>(ei, epos, asrc, adst, wbuf);
    agg_kernel<<<waveBlocks, 256, 0, stream>>>(offs, csr, wbuf, hA, b2, hB, 0);

    // pool
    pool_kernel<<<dim3(NGRAPH, 8), 256, 0, stream>>>(hB, counts, out);
}